// Round 1
// baseline (637.524 us; speedup 1.0000x reference)
//
#include <hip/hip_runtime.h>

// Problem constants
#define B_ 2
#define N_ 4096
#define H_ 256
#define HEADS_ 4
#define DH_ 64

typedef _Float16 f16;
typedef f16 f16x8 __attribute__((ext_vector_type(8)));
typedef f16 f16x4 __attribute__((ext_vector_type(4)));
typedef float f32x4 __attribute__((ext_vector_type(4)));

// Workspace layout (units: f16 elements)
//  h_h  : 0         2097152   (dead after proj; rsum_ws f32 reuses this region)
//  W_h  : 2097152   4*65536 (Wq,Wk,Wv,Wo)
//  Q_h  : 2359296   2097152   (b,head,n,dh), pre-scaled by 1/8
//  K_h  : 4456448   2097152   (b,head,n,dh)
//  V_t  : 6553600   2097152   (b,head,dh,n)
//  O_h  : 8650752   2097152   (b,n,256)
//  adjb : 10747904  1048576   2 MB packed adjacency bitmask
// total ~24 MB (p_ws eliminated: mean is recomputed, not materialized)

#define HOUT_OFF 2097152  // float offset of attn part in d_out

__global__ __launch_bounds__(256) void cvt_kernel(
    const float* __restrict__ h, const float* __restrict__ Wq,
    const float* __restrict__ Wk, const float* __restrict__ Wv,
    const float* __restrict__ Wo, f16* __restrict__ ws) {
  int i = blockIdx.x * 256 + threadIdx.x;
  const int NH = 2097152;
  if (i < NH) {
    ws[i] = (f16)h[i];
  } else if (i < NH + 4 * 65536) {
    int j = i - NH;
    int sel = j >> 16;
    int k = j & 65535;
    const float* src = sel == 0 ? Wq : sel == 1 ? Wk : sel == 2 ? Wv : Wo;
    ws[i] = (f16)src[k];
  }
}

// Pack adj (int32 0/1, NxN) into bit-mask: adjb[row*64 + j/64] bit (j&63).
__global__ __launch_bounds__(256) void pack_adj_kernel(
    const int* __restrict__ adj, unsigned long long* __restrict__ adjb) {
  int g = blockIdx.x * 256 + threadIdx.x;
  int lane = threadIdx.x & 63;
  int av = adj[g] != 0;
  unsigned long long m = __ballot(av);
  if (lane == 0) adjb[g >> 6] = m;
}

// QKV projection. grid=(128, 12): y = wsel*4 + head. Block = 4 waves, tile 64x64.
__global__ __launch_bounds__(256) void proj_kernel(
    const f16* __restrict__ hh, const f16* __restrict__ Wh,
    const float* __restrict__ bq, const float* __restrict__ bk,
    const float* __restrict__ bv, f16* __restrict__ Qh, f16* __restrict__ Kh,
    f16* __restrict__ Vt) {
  const int tid = threadIdx.x;
  const int lane = tid & 63, w = tid >> 6;
  const int q = lane >> 4, c = lane & 15;
  const int wsel = blockIdx.y >> 2, head = blockIdx.y & 3;
  const int m0 = blockIdx.x * 64 + w * 16;
  const f16* W = Wh + wsel * 65536;
  const int o0 = head * 64;

  f32x4 acc[4] = {};
  for (int k0 = 0; k0 < 256; k0 += 32) {
    f16x8 a = *(const f16x8*)(hh + (size_t)(m0 + c) * 256 + k0 + q * 8);
#pragma unroll
    for (int cg = 0; cg < 4; ++cg) {
      f16x8 bfr = *(const f16x8*)(W + (size_t)(o0 + cg * 16 + c) * 256 + k0 + q * 8);
      acc[cg] = __builtin_amdgcn_mfma_f32_16x16x32_f16(a, bfr, acc[cg], 0, 0, 0);
    }
  }
  const int b = m0 >> 12, n = m0 & 4095;
  const float* bias = wsel == 0 ? bq : wsel == 1 ? bk : bv;
  if (wsel == 2) {
#pragma unroll
    for (int cg = 0; cg < 4; ++cg) {
      int dh = cg * 16 + c;
      float bb = bias[o0 + dh];
      f16x4 v;
#pragma unroll
      for (int r = 0; r < 4; ++r) v[r] = (f16)(acc[cg][r] + bb);
      *(f16x4*)(Vt + ((size_t)(b * HEADS_ + head) * DH_ + dh) * N_ + n + q * 4) = v;
    }
  } else {
    f16* dst = wsel == 0 ? Qh : Kh;
    const float scale = wsel == 0 ? 0.125f : 1.0f;
#pragma unroll
    for (int cg = 0; cg < 4; ++cg) {
      int dh = cg * 16 + c;
      float bb = bias[o0 + dh];
#pragma unroll
      for (int r = 0; r < 4; ++r)
        dst[((size_t)(b * HEADS_ + head) * N_ + n + q * 4 + r) * DH_ + dh] =
            (f16)((acc[cg][r] + bb) * scale);
    }
  }
}

#define TS 68  // LDS p-tile row stride (f32); rows 16B-aligned (68*4=272=17*16)
#define WTILE (16 * TS)

// ---------------- pass A: row-sums (linv) + PV -> O ----------------
// grid = 2048 blocks: bh = gid&7 (XCD-pinned), i-block = gid>>3 (16 rows).
// block = 256 thr = 4 waves = 4 j-quarters. No per-iteration barriers.
// Identical math to the old attn_ph minus the 266 MB e-store.
__global__ __launch_bounds__(256, 3) void attn_sum_kernel(
    const f16* __restrict__ Qh, const f16* __restrict__ Kh,
    const f16* __restrict__ Vt, const float* __restrict__ tau,
    const uint2* __restrict__ adjb, const float* __restrict__ cw,
    f16* __restrict__ Oh, float* __restrict__ rsum_ws) {
  __shared__ float lds[4 * WTILE];
  __shared__ float lred[4][16];
  const int gid = blockIdx.x;
  const int bh = gid & 7;
  const int b = bh >> 2, h = bh & 3;
  const int i0 = (gid >> 3) * 16;
  const int tid = threadIdx.x;
  const int lane = tid & 63, jq = tid >> 6;
  const int q = lane >> 4, c = lane & 15;

  const f16* Qbase = Qh + ((size_t)bh * N_ + i0 + c) * DH_;
  f16x8 a0 = *(const f16x8*)(Qbase + q * 8);
  f16x8 a1 = *(const f16x8*)(Qbase + 32 + q * 8);

  const float cw_h = cw[h];  // cb cancels in softmax
  float tau_i[4];
#pragma unroll
  for (int r = 0; r < 4; ++r) tau_i[r] = tau[b * N_ + i0 + q * 4 + r];
  const f16* Kb = Kh + (size_t)bh * N_ * DH_;
  const f16* Vb = Vt + (size_t)bh * DH_ * N_;
  const float* taub = tau + b * N_;
  const int jbase = jq * 1024;

  float lsum[4] = {0.f, 0.f, 0.f, 0.f};
  f32x4 oacc[4] = {};
  float* myp = lds + jq * WTILE;

  for (int it = 0; it < 16; ++it) {
    const int j0 = jbase + it * 64;
    // ==== issue ALL of this iteration's loads up front (24 vmem ops) ====
    f16x8 kf[8], vf[8];
    uint2 aw[4];
    float tj[4];
#pragma unroll
    for (int cg = 0; cg < 4; ++cg) {
      const f16* Kr = Kb + (size_t)(j0 + cg * 16 + c) * DH_ + q * 8;
      kf[2 * cg] = *(const f16x8*)Kr;
      kf[2 * cg + 1] = *(const f16x8*)(Kr + 32);
    }
#pragma unroll
    for (int ks = 0; ks < 2; ++ks)
#pragma unroll
      for (int cg = 0; cg < 4; ++cg)
        vf[ks * 4 + cg] =
            *(const f16x8*)(Vb + (size_t)(cg * 16 + c) * N_ + j0 + ks * 32 + q * 8);
#pragma unroll
    for (int r = 0; r < 4; ++r)
      aw[r] = adjb[(size_t)(i0 + q * 4 + r) * 64 + (j0 >> 6)];
#pragma unroll
    for (int cg = 0; cg < 4; ++cg) tj[cg] = taub[j0 + cg * 16 + c];

    // ==== QK^T -> e = mask*exp(s) -> LDS tile (+ row-sum accumulate) ====
#pragma unroll
    for (int cg = 0; cg < 4; ++cg) {
      f32x4 s = {};
      s = __builtin_amdgcn_mfma_f32_16x16x32_f16(a0, kf[2 * cg], s, 0, 0, 0);
      s = __builtin_amdgcn_mfma_f32_16x16x32_f16(a1, kf[2 * cg + 1], s, 0, 0, 0);
      const float credj = cw_h * tj[cg];
      const unsigned shift = (cg & 1) * 16 + c;
#pragma unroll
      for (int r = 0; r < 4; ++r) {
        unsigned mword = (cg < 2) ? aw[r].x : aw[r].y;
        float e = __expf(s[r] + credj * tau_i[r]);
        e = ((mword >> shift) & 1) ? e : 0.f;
        lsum[r] += e;
        myp[(q * 4 + r) * TS + cg * 16 + c] = e;
      }
    }
    // ==== PV with unnormalized e (A-fragment from own LDS tile) ====
#pragma unroll
    for (int ks = 0; ks < 2; ++ks) {
      f32x4 plo = *(f32x4*)(myp + c * TS + ks * 32 + q * 8);
      f32x4 phi = *(f32x4*)(myp + c * TS + ks * 32 + q * 8 + 4);
      f16x8 pa;
#pragma unroll
      for (int t = 0; t < 4; ++t) {
        pa[t] = (f16)plo[t];
        pa[4 + t] = (f16)phi[t];
      }
#pragma unroll
      for (int cg = 0; cg < 4; ++cg)
        oacc[cg] =
            __builtin_amdgcn_mfma_f32_16x16x32_f16(pa, vf[ks * 4 + cg], oacc[cg], 0, 0, 0);
    }
  }

  // ---- combine row sums across j-quarters -> linv ----
#pragma unroll
  for (int r = 0; r < 4; ++r) {
    float v = lsum[r];
    v += __shfl_xor(v, 1);
    v += __shfl_xor(v, 2);
    v += __shfl_xor(v, 4);
    v += __shfl_xor(v, 8);
    lsum[r] = v;
  }
  if (c == 0) {
#pragma unroll
    for (int r = 0; r < 4; ++r) lred[jq][q * 4 + r] = lsum[r];
  }
  __syncthreads();
  float linv[4];
#pragma unroll
  for (int r = 0; r < 4; ++r)
    linv[r] = 1.0f / (lred[0][q * 4 + r] + lred[1][q * 4 + r] +
                      lred[2][q * 4 + r] + lred[3][q * 4 + r]);
  if (jq == 0 && c == 0) {
#pragma unroll
    for (int r = 0; r < 4; ++r) rsum_ws[bh * N_ + i0 + q * 4 + r] = linv[r];
  }

  // ---- combine PV partials across j-quarters, scale, write O ----
  if (jq != 0) {
#pragma unroll
    for (int cg = 0; cg < 4; ++cg)
#pragma unroll
      for (int r = 0; r < 4; ++r) myp[(cg * 4 + r) * 64 + lane] = oacc[cg][r];
  }
  __syncthreads();
  if (jq == 0) {
#pragma unroll
    for (int cg = 0; cg < 4; ++cg)
#pragma unroll
      for (int r = 0; r < 4; ++r) {
        float v = oacc[cg][r];
#pragma unroll
        for (int jj = 1; jj < 4; ++jj)
          v += lds[jj * WTILE + (cg * 4 + r) * 64 + lane];
        Oh[((size_t)(b * N_) + i0 + q * 4 + r) * H_ + h * 64 + cg * 16 + c] =
            (f16)(v * linv[r]);
      }
  }
}

// ---------------- pass B: head-mean via QK^T recompute ----------------
// grid = 2048: gid&1 = b, (gid>>1)&3 = j-quarter (gid&7 XCD-pinned -> each
// XCD's L2 holds one (b,jq) K-slice: 4 heads x 1024 rows x 128 B = 512 KB),
// gid>>3 = i-block. Block = 4 waves; each wave owns whole j-tiles (64 j) and
// loops the 4 heads sequentially -> no barriers, exact same MFMA sequence as
// pass A -> e values bit-identical to the ones summed into linv.
__global__ __launch_bounds__(256, 4) void attn_mean_kernel(
    const f16* __restrict__ Qh, const f16* __restrict__ Kh,
    const float* __restrict__ tau, const uint2* __restrict__ adjb,
    const float* __restrict__ cw, const float* __restrict__ linv_ws,
    float* __restrict__ out) {
  const int gid = blockIdx.x;
  const int b = gid & 1;
  const int jq = (gid >> 1) & 3;
  const int i0 = (gid >> 3) * 16;
  const int tid = threadIdx.x;
  const int lane = tid & 63, w = tid >> 6;
  const int q = lane >> 4, c = lane & 15;

  // Q fragments + per-row linv*0.25 for all 4 heads (registers)
  f16x8 a0[4], a1[4];
  float li[4][4];
  float cwh[4];
#pragma unroll
  for (int h = 0; h < 4; ++h) {
    const f16* Qbase = Qh + ((size_t)(b * 4 + h) * N_ + i0 + c) * DH_;
    a0[h] = *(const f16x8*)(Qbase + q * 8);
    a1[h] = *(const f16x8*)(Qbase + 32 + q * 8);
    cwh[h] = cw[h];
#pragma unroll
    for (int r = 0; r < 4; ++r)
      li[h][r] = linv_ws[(b * 4 + h) * N_ + i0 + q * 4 + r] * 0.25f;
  }
  float tau_i[4];
#pragma unroll
  for (int r = 0; r < 4; ++r) tau_i[r] = tau[b * N_ + i0 + q * 4 + r];
  const float* taub = tau + b * N_;

  for (int it = 0; it < 4; ++it) {
    const int j0 = jq * 1024 + (it * 4 + w) * 64;
    // per-tile loads shared across heads
    uint2 aw[4];
#pragma unroll
    for (int r = 0; r < 4; ++r)
      aw[r] = adjb[(size_t)(i0 + q * 4 + r) * 64 + (j0 >> 6)];
    float tj[4];
#pragma unroll
    for (int cg = 0; cg < 4; ++cg) tj[cg] = taub[j0 + cg * 16 + c];

    f32x4 macc[4] = {};
#pragma unroll
    for (int h = 0; h < 4; ++h) {
      const f16* Kb = Kh + (size_t)(b * 4 + h) * N_ * DH_;
#pragma unroll
      for (int cg = 0; cg < 4; ++cg) {
        const f16* Kr = Kb + (size_t)(j0 + cg * 16 + c) * DH_ + q * 8;
        f16x8 k0 = *(const f16x8*)Kr;
        f16x8 k1 = *(const f16x8*)(Kr + 32);
        f32x4 s = {};
        s = __builtin_amdgcn_mfma_f32_16x16x32_f16(a0[h], k0, s, 0, 0, 0);
        s = __builtin_amdgcn_mfma_f32_16x16x32_f16(a1[h], k1, s, 0, 0, 0);
        const float credj = cwh[h] * tj[cg];
        const unsigned shift = (cg & 1) * 16 + c;
#pragma unroll
        for (int r = 0; r < 4; ++r) {
          unsigned mword = (cg < 2) ? aw[r].x : aw[r].y;
          float e = __expf(s[r] + credj * tau_i[r]);
          float lw = ((mword >> shift) & 1) ? li[h][r] : 0.f;
          macc[cg][r] += e * lw;
        }
      }
    }
    // direct store of the 16x64 f32 mean tile (rows contiguous 64 B sectors)
#pragma unroll
    for (int cg = 0; cg < 4; ++cg)
#pragma unroll
      for (int r = 0; r < 4; ++r)
        out[((size_t)(b * N_) + i0 + q * 4 + r) * N_ + j0 + cg * 16 + c] =
            macc[cg][r];
  }
}

// Output projection: h_out = O @ Wo^T + bo. grid=(128,4), block=4 waves, 64x64 tile.
__global__ __launch_bounds__(256) void oproj_kernel(
    const f16* __restrict__ Oh, const f16* __restrict__ Woh,
    const float* __restrict__ bo, float* __restrict__ out) {
  const int tid = threadIdx.x, lane = tid & 63, w = tid >> 6;
  const int q = lane >> 4, c = lane & 15;
  const int m0 = blockIdx.x * 64 + w * 16;
  const int o0 = blockIdx.y * 64;
  f32x4 acc[4] = {};
  for (int k0 = 0; k0 < 256; k0 += 32) {
    f16x8 a = *(const f16x8*)(Oh + (size_t)(m0 + c) * 256 + k0 + q * 8);
#pragma unroll
    for (int cg = 0; cg < 4; ++cg) {
      f16x8 bfr = *(const f16x8*)(Woh + (size_t)(o0 + cg * 16 + c) * 256 + k0 + q * 8);
      acc[cg] = __builtin_amdgcn_mfma_f32_16x16x32_f16(a, bfr, acc[cg], 0, 0, 0);
    }
  }
#pragma unroll
  for (int cg = 0; cg < 4; ++cg) {
    float bb = bo[o0 + cg * 16 + c];
#pragma unroll
    for (int r = 0; r < 4; ++r)
      out[(size_t)(m0 + q * 4 + r) * 256 + o0 + cg * 16 + c] = acc[cg][r] + bb;
  }
}

extern "C" void kernel_launch(void* const* d_in, const int* in_sizes, int n_in,
                              void* d_out, int out_size, void* d_ws,
                              size_t ws_size, hipStream_t stream) {
  const float* h   = (const float*)d_in[0];
  const float* tau = (const float*)d_in[1];
  const int*   adj = (const int*)d_in[2];
  const float* Wq  = (const float*)d_in[3];
  const float* bq  = (const float*)d_in[4];
  const float* Wk  = (const float*)d_in[5];
  const float* bk  = (const float*)d_in[6];
  const float* Wv  = (const float*)d_in[7];
  const float* bv  = (const float*)d_in[8];
  const float* cw  = (const float*)d_in[9];
  const float* Wo  = (const float*)d_in[11];
  const float* bo  = (const float*)d_in[12];
  float* out = (float*)d_out;

  f16* ws   = (f16*)d_ws;
  f16* h_h  = ws;
  f16* W_h  = ws + 2097152;
  f16* Wo_h = W_h + 3 * 65536;
  f16* Q_h  = ws + 2359296;
  f16* K_h  = ws + 4456448;
  f16* V_t  = ws + 6553600;
  f16* O_h  = ws + 8650752;
  unsigned long long* adjb = (unsigned long long*)(ws + 10747904);
  float* rsum_ws = (float*)ws;  // reuses dead h_h region (proj runs before attn)

  pack_adj_kernel<<<dim3(65536), dim3(256), 0, stream>>>(adj, adjb);
  cvt_kernel<<<dim3(9216), dim3(256), 0, stream>>>(h, Wq, Wk, Wv, Wo, ws);
  proj_kernel<<<dim3(128, 12), dim3(256), 0, stream>>>(h_h, W_h, bq, bk, bv, Q_h,
                                                       K_h, V_t);
  attn_sum_kernel<<<dim3(2048), dim3(256), 0, stream>>>(
      Q_h, K_h, V_t, tau, (const uint2*)adjb, cw, O_h, rsum_ws);
  attn_mean_kernel<<<dim3(2048), dim3(256), 0, stream>>>(
      Q_h, K_h, tau, (const uint2*)adjb, cw, rsum_ws, out + HOUT_OFF);
  oproj_kernel<<<dim3(128, 4), dim3(256), 0, stream>>>(O_h, Wo_h, bo, out);
}

// Round 2
// 427.493 us; speedup vs baseline: 1.4913x; 1.4913x over previous
//
#include <hip/hip_runtime.h>

// Problem constants
#define B_ 2
#define N_ 4096
#define H_ 256
#define HEADS_ 4
#define DH_ 64

typedef _Float16 f16;
typedef f16 f16x8 __attribute__((ext_vector_type(8)));
typedef f16 f16x4 __attribute__((ext_vector_type(4)));
typedef float f32x4 __attribute__((ext_vector_type(4)));

// Workspace layout (units: f16 elements)
//  h_h  : 0         2097152   (dead after proj; rsum_ws f32 reuses this region)
//  W_h  : 2097152   4*65536 (Wq,Wk,Wv,Wo)
//  Q_h  : 2359296   2097152   (b,head,n,dh), pre-scaled by 1/8
//  Kf   : 4456448   2097152   fragment-major K: [bh][t][half] 512-f16 frags
//  Vf   : 6553600   2097152   fragment-major V: [bh][jt][ks*4+cg] 512-f16 frags
//  O_h  : 8650752   2097152   (b,n,256)
//  adjb : 10747904  1048576   2 MB packed adjacency bitmask
// total ~24 MB

#define HOUT_OFF 2097152  // float offset of attn part in d_out

__global__ __launch_bounds__(256) void cvt_kernel(
    const float* __restrict__ h, const float* __restrict__ Wq,
    const float* __restrict__ Wk, const float* __restrict__ Wv,
    const float* __restrict__ Wo, f16* __restrict__ ws) {
  int i = blockIdx.x * 256 + threadIdx.x;
  const int NH = 2097152;
  if (i < NH) {
    ws[i] = (f16)h[i];
  } else if (i < NH + 4 * 65536) {
    int j = i - NH;
    int sel = j >> 16;
    int k = j & 65535;
    const float* src = sel == 0 ? Wq : sel == 1 ? Wk : sel == 2 ? Wv : Wo;
    ws[i] = (f16)src[k];
  }
}

// Pack adj (int32 0/1, NxN) into bit-mask: adjb[row*64 + j/64] bit (j&63).
__global__ __launch_bounds__(256) void pack_adj_kernel(
    const int* __restrict__ adj, unsigned long long* __restrict__ adjb) {
  int g = blockIdx.x * 256 + threadIdx.x;
  int lane = threadIdx.x & 63;
  int av = adj[g] != 0;
  unsigned long long m = __ballot(av);
  if (lane == 0) adjb[g >> 6] = m;
}

// QKV projection. grid=(128, 12): y = wsel*4 + head. Block = 4 waves, tile 64x64.
// K and V are written in FRAGMENT-MAJOR layout so attention waves load them as
// contiguous 1 KB bursts (lane*8) instead of 16-line scattered reads.
__global__ __launch_bounds__(256) void proj_kernel(
    const f16* __restrict__ hh, const f16* __restrict__ Wh,
    const float* __restrict__ bq, const float* __restrict__ bk,
    const float* __restrict__ bv, f16* __restrict__ Qh, f16* __restrict__ Kf,
    f16* __restrict__ Vf) {
  const int tid = threadIdx.x;
  const int lane = tid & 63, w = tid >> 6;
  const int q = lane >> 4, c = lane & 15;
  const int wsel = blockIdx.y >> 2, head = blockIdx.y & 3;
  const int m0 = blockIdx.x * 64 + w * 16;
  const f16* W = Wh + wsel * 65536;
  const int o0 = head * 64;

  f32x4 acc[4] = {};
  for (int k0 = 0; k0 < 256; k0 += 32) {
    f16x8 a = *(const f16x8*)(hh + (size_t)(m0 + c) * 256 + k0 + q * 8);
#pragma unroll
    for (int cg = 0; cg < 4; ++cg) {
      f16x8 bfr = *(const f16x8*)(W + (size_t)(o0 + cg * 16 + c) * 256 + k0 + q * 8);
      acc[cg] = __builtin_amdgcn_mfma_f32_16x16x32_f16(a, bfr, acc[cg], 0, 0, 0);
    }
  }
  const int b = m0 >> 12, n = m0 & 4095;
  const int bh2 = b * HEADS_ + head;
  if (wsel == 2) {
    // V fragment-major: Vf[bh][jt][ks*4+cg][lane_f*8+e],
    // lane_f=(jj>>3&3)*16+c, jj = j mod 64, e = jj&7.
    const int jt = n >> 6;
    f16* vbase = Vf + (((size_t)bh2 * 64 + jt) * 8) * 512;
#pragma unroll
    for (int cg = 0; cg < 4; ++cg) {
      float bb = bv[o0 + cg * 16 + c];
#pragma unroll
      for (int r = 0; r < 4; ++r) {
        int jj = w * 16 + q * 4 + r;
        vbase[(size_t)(((jj >> 5) * 4 + cg) * 512) + ((jj >> 3) & 3) * 128 +
              c * 8 + (jj & 7)] = (f16)(acc[cg][r] + bb);
      }
    }
  } else if (wsel == 1) {
    // K fragment-major: Kf[bh][t][half][lane_f*8+e],
    // lane_f = qf*16 + (row within 16-tile), e = c&7.
    const int t = n >> 4;
    f16* kbase = Kf + (((size_t)bh2 * 256 + t) * 2) * 512;
#pragma unroll
    for (int cg = 0; cg < 4; ++cg) {
      float bb = bk[o0 + cg * 16 + c];
      const int half = cg >> 1;
      const int qf = ((cg & 1) * 16 + c) >> 3;
      f16* kb2 = kbase + half * 512 + qf * 128 + (c & 7);
#pragma unroll
      for (int r = 0; r < 4; ++r) kb2[(q * 4 + r) * 8] = (f16)(acc[cg][r] + bb);
    }
  } else {
    // Q keeps (n, dh) layout, pre-scaled by 1/8
#pragma unroll
    for (int cg = 0; cg < 4; ++cg) {
      int dh = cg * 16 + c;
      float bb = bq[o0 + dh];
#pragma unroll
      for (int r = 0; r < 4; ++r)
        Qh[((size_t)bh2 * N_ + n + q * 4 + r) * DH_ + dh] =
            (f16)((acc[cg][r] + bb) * 0.125f);
    }
  }
}

#define TS 68  // LDS p-tile row stride (f32); rows 16B-aligned (68*4=272=17*16)
#define WTILE (16 * TS)

// ---------------- pass A: row-sums (linv) + PV -> O ----------------
// grid = 2048 blocks: bh = gid&7 (XCD-pinned), i-block = gid>>3 (16 rows).
// block = 256 thr = 4 waves = 4 j-quarters. K-fragments double-buffered
// (prefetch next j-tile under current PV); V/adj/tau issued at iter top.
// No vmcnt(0) drains inside the loop.
__global__ __launch_bounds__(256) void attn_sum_kernel(
    const f16* __restrict__ Qh, const f16* __restrict__ Kf,
    const f16* __restrict__ Vf, const float* __restrict__ tau,
    const uint2* __restrict__ adjb, const float* __restrict__ cw,
    f16* __restrict__ Oh, float* __restrict__ rsum_ws) {
  __shared__ float lds[4 * WTILE];
  __shared__ float lred[4][16];
  const int gid = blockIdx.x;
  const int bh = gid & 7;
  const int b = bh >> 2, h = bh & 3;
  const int i0 = (gid >> 3) * 16;
  const int tid = threadIdx.x;
  const int lane = tid & 63, jq = tid >> 6;
  const int q = lane >> 4, c = lane & 15;

  const f16* Qbase = Qh + ((size_t)bh * N_ + i0 + c) * DH_;
  f16x8 a0 = *(const f16x8*)(Qbase + q * 8);
  f16x8 a1 = *(const f16x8*)(Qbase + 32 + q * 8);

  const float cw_h = cw[h];  // cb cancels in softmax
  float tau_i[4];
#pragma unroll
  for (int r = 0; r < 4; ++r) tau_i[r] = tau[b * N_ + i0 + q * 4 + r];
  const f16* Kfb = Kf + (size_t)bh * 262144 + lane * 8;
  const f16* Vfb = Vf + (size_t)bh * 262144 + lane * 8;
  const float* taub = tau + b * N_;
  const int jbase = jq * 1024;

  float lsum[4] = {0.f, 0.f, 0.f, 0.f};
  f32x4 oacc[4] = {};
  float* myp = lds + jq * WTILE;

  // prologue: K fragments for it=0
  f16x8 kf[2][8];
  f16x8 vf[8];
  {
    const f16* kt = Kfb + (size_t)(jbase >> 4) * 1024;
#pragma unroll
    for (int f = 0; f < 8; ++f) kf[0][f] = *(const f16x8*)(kt + f * 512);
  }

#pragma unroll 2
  for (int it = 0; it < 16; ++it) {
    const int cur = it & 1, nx = cur ^ 1;
    const int j0 = jbase + it * 64;
    const int jn = j0 + (it < 15 ? 64 : 0);  // predicated: no OOB on last iter
    // ==== issue this iter's adj/tau then V (consumed later) ====
    uint2 aw[4];
    float tj[4];
#pragma unroll
    for (int r = 0; r < 4; ++r)
      aw[r] = adjb[(size_t)(i0 + q * 4 + r) * 64 + (j0 >> 6)];
#pragma unroll
    for (int cg = 0; cg < 4; ++cg) tj[cg] = taub[j0 + cg * 16 + c];
    {
      const f16* vt = Vfb + (size_t)(j0 >> 6) * 4096;
#pragma unroll
      for (int f = 0; f < 8; ++f) vf[f] = *(const f16x8*)(vt + f * 512);
    }

    // ==== QK^T (kf[cur] resident) -> e = mask*exp(s) -> LDS (+row-sum) ====
#pragma unroll
    for (int cg = 0; cg < 4; ++cg) {
      f32x4 s = {};
      s = __builtin_amdgcn_mfma_f32_16x16x32_f16(a0, kf[cur][2 * cg], s, 0, 0, 0);
      s = __builtin_amdgcn_mfma_f32_16x16x32_f16(a1, kf[cur][2 * cg + 1], s, 0, 0, 0);
      const float credj = cw_h * tj[cg];
      const unsigned shift = (cg & 1) * 16 + c;
#pragma unroll
      for (int r = 0; r < 4; ++r) {
        unsigned mword = (cg < 2) ? aw[r].x : aw[r].y;
        float e = __expf(s[r] + credj * tau_i[r]);
        e = ((mword >> shift) & 1) ? e : 0.f;
        lsum[r] += e;
        myp[(q * 4 + r) * TS + cg * 16 + c] = e;
      }
    }
    // ==== prefetch next iter's K fragments ====
    {
      const f16* kt = Kfb + (size_t)(jn >> 4) * 1024;
#pragma unroll
      for (int f = 0; f < 8; ++f) kf[nx][f] = *(const f16x8*)(kt + f * 512);
    }
    // ==== PV with unnormalized e (A-fragment from own LDS tile) ====
#pragma unroll
    for (int ks = 0; ks < 2; ++ks) {
      f32x4 plo = *(f32x4*)(myp + c * TS + ks * 32 + q * 8);
      f32x4 phi = *(f32x4*)(myp + c * TS + ks * 32 + q * 8 + 4);
      f16x8 pa;
#pragma unroll
      for (int t = 0; t < 4; ++t) {
        pa[t] = (f16)plo[t];
        pa[4 + t] = (f16)phi[t];
      }
#pragma unroll
      for (int cg = 0; cg < 4; ++cg)
        oacc[cg] =
            __builtin_amdgcn_mfma_f32_16x16x32_f16(pa, vf[ks * 4 + cg], oacc[cg], 0, 0, 0);
    }
  }

  // ---- combine row sums across j-quarters -> linv ----
#pragma unroll
  for (int r = 0; r < 4; ++r) {
    float v = lsum[r];
    v += __shfl_xor(v, 1);
    v += __shfl_xor(v, 2);
    v += __shfl_xor(v, 4);
    v += __shfl_xor(v, 8);
    lsum[r] = v;
  }
  if (c == 0) {
#pragma unroll
    for (int r = 0; r < 4; ++r) lred[jq][q * 4 + r] = lsum[r];
  }
  __syncthreads();
  float linv[4];
#pragma unroll
  for (int r = 0; r < 4; ++r)
    linv[r] = 1.0f / (lred[0][q * 4 + r] + lred[1][q * 4 + r] +
                      lred[2][q * 4 + r] + lred[3][q * 4 + r]);
  if (jq == 0 && c == 0) {
#pragma unroll
    for (int r = 0; r < 4; ++r) rsum_ws[bh * N_ + i0 + q * 4 + r] = linv[r];
  }

  // ---- combine PV partials across j-quarters, scale, write O ----
  if (jq != 0) {
#pragma unroll
    for (int cg = 0; cg < 4; ++cg)
#pragma unroll
      for (int r = 0; r < 4; ++r) myp[(cg * 4 + r) * 64 + lane] = oacc[cg][r];
  }
  __syncthreads();
  if (jq == 0) {
#pragma unroll
    for (int cg = 0; cg < 4; ++cg)
#pragma unroll
      for (int r = 0; r < 4; ++r) {
        float v = oacc[cg][r];
#pragma unroll
        for (int jj = 1; jj < 4; ++jj)
          v += lds[jj * WTILE + (cg * 4 + r) * 64 + lane];
        Oh[((size_t)(b * N_) + i0 + q * 4 + r) * H_ + h * 64 + cg * 16 + c] =
            (f16)(v * linv[r]);
      }
  }
}

// ---------------- pass B: head-mean via QK^T recompute ----------------
// grid = 2048: gid&1 = b, (gid>>1)&3 = jq (gid&7 XCD-pinned), gid>>3 = i-block.
// Each wave owns whole 64-j tiles, loops the 4 heads with K-fragment
// double-buffering (prefetch head h+1 under head h's MFMA+exp).
__global__ __launch_bounds__(256) void attn_mean_kernel(
    const f16* __restrict__ Qh, const f16* __restrict__ Kf,
    const float* __restrict__ tau, const uint2* __restrict__ adjb,
    const float* __restrict__ cw, const float* __restrict__ linv_ws,
    float* __restrict__ out) {
  const int gid = blockIdx.x;
  const int b = gid & 1;
  const int jq = (gid >> 1) & 3;
  const int i0 = (gid >> 3) * 16;
  const int tid = threadIdx.x;
  const int lane = tid & 63, w = tid >> 6;
  const int q = lane >> 4, c = lane & 15;

  // Q fragments + per-row linv*0.25 for all 4 heads (registers)
  f16x8 a0[4], a1[4];
  float li[4][4];
  float cwh[4];
#pragma unroll
  for (int h = 0; h < 4; ++h) {
    const f16* Qbase = Qh + ((size_t)(b * 4 + h) * N_ + i0 + c) * DH_;
    a0[h] = *(const f16x8*)(Qbase + q * 8);
    a1[h] = *(const f16x8*)(Qbase + 32 + q * 8);
    cwh[h] = cw[h];
#pragma unroll
    for (int r = 0; r < 4; ++r)
      li[h][r] = linv_ws[(b * 4 + h) * N_ + i0 + q * 4 + r] * 0.25f;
  }
  float tau_i[4];
#pragma unroll
  for (int r = 0; r < 4; ++r) tau_i[r] = tau[b * N_ + i0 + q * 4 + r];
  const float* taub = tau + b * N_;

  for (int it = 0; it < 4; ++it) {
    const int j0 = jq * 1024 + (it * 4 + w) * 64;
    uint2 aw[4];
#pragma unroll
    for (int r = 0; r < 4; ++r)
      aw[r] = adjb[(size_t)(i0 + q * 4 + r) * 64 + (j0 >> 6)];
    float tj[4];
#pragma unroll
    for (int cg = 0; cg < 4; ++cg) tj[cg] = taub[j0 + cg * 16 + c];

    // K fragment base for this j-tile, head 0; head stride = 262144 f16
    const f16* KfT = Kf + (size_t)(b * 4) * 262144 + (size_t)(j0 >> 4) * 1024 +
                     lane * 8;
    f16x8 kf2[2][8];
#pragma unroll
    for (int f = 0; f < 8; ++f) kf2[0][f] = *(const f16x8*)(KfT + f * 512);

    f32x4 macc[4] = {};
#pragma unroll
    for (int h = 0; h < 4; ++h) {
      const int cur = h & 1, nx = cur ^ 1;
      if (h < 3) {
        const f16* Kn = KfT + (size_t)(h + 1) * 262144;
#pragma unroll
        for (int f = 0; f < 8; ++f) kf2[nx][f] = *(const f16x8*)(Kn + f * 512);
      }
#pragma unroll
      for (int cg = 0; cg < 4; ++cg) {
        f32x4 s = {};
        s = __builtin_amdgcn_mfma_f32_16x16x32_f16(a0[h], kf2[cur][2 * cg], s, 0, 0, 0);
        s = __builtin_amdgcn_mfma_f32_16x16x32_f16(a1[h], kf2[cur][2 * cg + 1], s, 0, 0, 0);
        const float credj = cwh[h] * tj[cg];
        const unsigned shift = (cg & 1) * 16 + c;
#pragma unroll
        for (int r = 0; r < 4; ++r) {
          unsigned mword = (cg < 2) ? aw[r].x : aw[r].y;
          float e = __expf(s[r] + credj * tau_i[r]);
          float lw = ((mword >> shift) & 1) ? li[h][r] : 0.f;
          macc[cg][r] += e * lw;
        }
      }
    }
    // direct store of the 16x64 f32 mean tile (16-lane rows = full 64 B lines)
#pragma unroll
    for (int cg = 0; cg < 4; ++cg)
#pragma unroll
      for (int r = 0; r < 4; ++r)
        out[((size_t)(b * N_) + i0 + q * 4 + r) * N_ + j0 + cg * 16 + c] =
            macc[cg][r];
  }
}

// Output projection: h_out = O @ Wo^T + bo. grid=(128,4), block=4 waves, 64x64 tile.
__global__ __launch_bounds__(256) void oproj_kernel(
    const f16* __restrict__ Oh, const f16* __restrict__ Woh,
    const float* __restrict__ bo, float* __restrict__ out) {
  const int tid = threadIdx.x, lane = tid & 63, w = tid >> 6;
  const int q = lane >> 4, c = lane & 15;
  const int m0 = blockIdx.x * 64 + w * 16;
  const int o0 = blockIdx.y * 64;
  f32x4 acc[4] = {};
  for (int k0 = 0; k0 < 256; k0 += 32) {
    f16x8 a = *(const f16x8*)(Oh + (size_t)(m0 + c) * 256 + k0 + q * 8);
#pragma unroll
    for (int cg = 0; cg < 4; ++cg) {
      f16x8 bfr = *(const f16x8*)(Woh + (size_t)(o0 + cg * 16 + c) * 256 + k0 + q * 8);
      acc[cg] = __builtin_amdgcn_mfma_f32_16x16x32_f16(a, bfr, acc[cg], 0, 0, 0);
    }
  }
#pragma unroll
  for (int cg = 0; cg < 4; ++cg) {
    float bb = bo[o0 + cg * 16 + c];
#pragma unroll
    for (int r = 0; r < 4; ++r)
      out[(size_t)(m0 + q * 4 + r) * 256 + o0 + cg * 16 + c] = acc[cg][r] + bb;
  }
}

extern "C" void kernel_launch(void* const* d_in, const int* in_sizes, int n_in,
                              void* d_out, int out_size, void* d_ws,
                              size_t ws_size, hipStream_t stream) {
  const float* h   = (const float*)d_in[0];
  const float* tau = (const float*)d_in[1];
  const int*   adj = (const int*)d_in[2];
  const float* Wq  = (const float*)d_in[3];
  const float* bq  = (const float*)d_in[4];
  const float* Wk  = (const float*)d_in[5];
  const float* bk  = (const float*)d_in[6];
  const float* Wv  = (const float*)d_in[7];
  const float* bv  = (const float*)d_in[8];
  const float* cw  = (const float*)d_in[9];
  const float* Wo  = (const float*)d_in[11];
  const float* bo  = (const float*)d_in[12];
  float* out = (float*)d_out;

  f16* ws   = (f16*)d_ws;
  f16* h_h  = ws;
  f16* W_h  = ws + 2097152;
  f16* Wo_h = W_h + 3 * 65536;
  f16* Q_h  = ws + 2359296;
  f16* K_f  = ws + 4456448;
  f16* V_f  = ws + 6553600;
  f16* O_h  = ws + 8650752;
  unsigned long long* adjb = (unsigned long long*)(ws + 10747904);
  float* rsum_ws = (float*)ws;  // reuses dead h_h region (proj runs before attn)

  pack_adj_kernel<<<dim3(65536), dim3(256), 0, stream>>>(adj, adjb);
  cvt_kernel<<<dim3(9216), dim3(256), 0, stream>>>(h, Wq, Wk, Wv, Wo, ws);
  proj_kernel<<<dim3(128, 12), dim3(256), 0, stream>>>(h_h, W_h, bq, bk, bv, Q_h,
                                                       K_f, V_f);
  attn_sum_kernel<<<dim3(2048), dim3(256), 0, stream>>>(
      Q_h, K_f, V_f, tau, (const uint2*)adjb, cw, O_h, rsum_ws);
  attn_mean_kernel<<<dim3(2048), dim3(256), 0, stream>>>(
      Q_h, K_f, tau, (const uint2*)adjb, cw, rsum_ws, out + HOUT_OFF);
  oproj_kernel<<<dim3(128, 4), dim3(256), 0, stream>>>(O_h, Wo_h, bo, out);
}

// Round 3
// 392.039 us; speedup vs baseline: 1.6262x; 1.0904x over previous
//
#include <hip/hip_runtime.h>

// Problem constants
#define B_ 2
#define N_ 4096
#define H_ 256
#define HEADS_ 4
#define DH_ 64

typedef _Float16 f16;
typedef f16 f16x8 __attribute__((ext_vector_type(8)));
typedef f16 f16x4 __attribute__((ext_vector_type(4)));
typedef float f32x4 __attribute__((ext_vector_type(4)));

// Workspace layout (units: f16 elements)
//  h_h  : 0         2097152   (dead after proj; rsum_ws f32 reuses this region)
//  W_h  : 2097152   4*65536 (Wq,Wk,Wv,Wo)
//  Q_h  : 2359296   2097152   (b,head,n,dh), pre-scaled by 1/8
//  Kf   : 4456448   2097152   fragment-major K: [bh][t][half] 512-f16 frags
//  Vf   : 6553600   2097152   fragment-major V: [bh][jt][ks*4+cg] 512-f16 frags
//  O_h  : 8650752   2097152   (b,n,256)
//  adjb : 10747904  1048576   2 MB packed adjacency bitmask
// total ~24 MB

#define HOUT_OFF 2097152  // float offset of attn part in d_out

__global__ __launch_bounds__(256) void cvt_kernel(
    const float* __restrict__ h, const float* __restrict__ Wq,
    const float* __restrict__ Wk, const float* __restrict__ Wv,
    const float* __restrict__ Wo, f16* __restrict__ ws) {
  int i = blockIdx.x * 256 + threadIdx.x;
  const int NH = 2097152;
  if (i < NH) {
    ws[i] = (f16)h[i];
  } else if (i < NH + 4 * 65536) {
    int j = i - NH;
    int sel = j >> 16;
    int k = j & 65535;
    const float* src = sel == 0 ? Wq : sel == 1 ? Wk : sel == 2 ? Wv : Wo;
    ws[i] = (f16)src[k];
  }
}

// Pack adj (int32 0/1, NxN) into bit-mask: adjb[row*64 + j/64] bit (j&63).
__global__ __launch_bounds__(256) void pack_adj_kernel(
    const int* __restrict__ adj, unsigned long long* __restrict__ adjb) {
  int g = blockIdx.x * 256 + threadIdx.x;
  int lane = threadIdx.x & 63;
  int av = adj[g] != 0;
  unsigned long long m = __ballot(av);
  if (lane == 0) adjb[g >> 6] = m;
}

// QKV projection. grid=(128, 12): y = wsel*4 + head. Block = 4 waves, tile 64x64.
// K and V are written in FRAGMENT-MAJOR layout so attention waves load them as
// contiguous 1 KB bursts (lane*8) instead of 16-line scattered reads.
__global__ __launch_bounds__(256) void proj_kernel(
    const f16* __restrict__ hh, const f16* __restrict__ Wh,
    const float* __restrict__ bq, const float* __restrict__ bk,
    const float* __restrict__ bv, f16* __restrict__ Qh, f16* __restrict__ Kf,
    f16* __restrict__ Vf) {
  const int tid = threadIdx.x;
  const int lane = tid & 63, w = tid >> 6;
  const int q = lane >> 4, c = lane & 15;
  const int wsel = blockIdx.y >> 2, head = blockIdx.y & 3;
  const int m0 = blockIdx.x * 64 + w * 16;
  const f16* W = Wh + wsel * 65536;
  const int o0 = head * 64;

  f32x4 acc[4] = {};
  for (int k0 = 0; k0 < 256; k0 += 32) {
    f16x8 a = *(const f16x8*)(hh + (size_t)(m0 + c) * 256 + k0 + q * 8);
#pragma unroll
    for (int cg = 0; cg < 4; ++cg) {
      f16x8 bfr = *(const f16x8*)(W + (size_t)(o0 + cg * 16 + c) * 256 + k0 + q * 8);
      acc[cg] = __builtin_amdgcn_mfma_f32_16x16x32_f16(a, bfr, acc[cg], 0, 0, 0);
    }
  }
  const int b = m0 >> 12, n = m0 & 4095;
  const int bh2 = b * HEADS_ + head;
  if (wsel == 2) {
    // V fragment-major: Vf[bh][jt][ks*4+cg][lane_f*8+e],
    // lane_f=(jj>>3&3)*16+c, jj = j mod 64, e = jj&7.
    const int jt = n >> 6;
    f16* vbase = Vf + (((size_t)bh2 * 64 + jt) * 8) * 512;
#pragma unroll
    for (int cg = 0; cg < 4; ++cg) {
      float bb = bv[o0 + cg * 16 + c];
#pragma unroll
      for (int r = 0; r < 4; ++r) {
        int jj = w * 16 + q * 4 + r;
        vbase[(size_t)(((jj >> 5) * 4 + cg) * 512) + ((jj >> 3) & 3) * 128 +
              c * 8 + (jj & 7)] = (f16)(acc[cg][r] + bb);
      }
    }
  } else if (wsel == 1) {
    // K fragment-major: Kf[bh][t][half][lane_f*8+e],
    // lane_f = qf*16 + (row within 16-tile), e = c&7.
    const int t = n >> 4;
    f16* kbase = Kf + (((size_t)bh2 * 256 + t) * 2) * 512;
#pragma unroll
    for (int cg = 0; cg < 4; ++cg) {
      float bb = bk[o0 + cg * 16 + c];
      const int half = cg >> 1;
      const int qf = ((cg & 1) * 16 + c) >> 3;
      f16* kb2 = kbase + half * 512 + qf * 128 + (c & 7);
#pragma unroll
      for (int r = 0; r < 4; ++r) kb2[(q * 4 + r) * 8] = (f16)(acc[cg][r] + bb);
    }
  } else {
    // Q keeps (n, dh) layout, pre-scaled by 1/8
#pragma unroll
    for (int cg = 0; cg < 4; ++cg) {
      int dh = cg * 16 + c;
      float bb = bq[o0 + dh];
#pragma unroll
      for (int r = 0; r < 4; ++r)
        Qh[((size_t)bh2 * N_ + n + q * 4 + r) * DH_ + dh] =
            (f16)((acc[cg][r] + bb) * 0.125f);
    }
  }
}

#define TS 68  // LDS p-tile row stride (f32); rows 16B-aligned (68*4=272=17*16)
#define WTILE (16 * TS)

// ---------------- pass A: row-sums (linv) + PV -> O ----------------
// grid = 512 blocks: bh = gid&7 (XCD-pinned: K+V of one bh = 1 MB, L2-hot),
// i-block = gid>>3 (64 rows). Block = 4 waves = 4 j-quarters; each wave
// processes 4 i-groups (64 Q rows) per K/V tile -> 4x load amortization and
// 4 independent MFMA/exp chains for latency hiding. Accumulators
// (oacc[4][4]+lsum+a-frags ~130 VGPR) force a generous register allocation.
__global__ __launch_bounds__(256, 2) void attn_sum_kernel(
    const f16* __restrict__ Qh, const f16* __restrict__ Kf,
    const f16* __restrict__ Vf, const float* __restrict__ tau,
    const uint2* __restrict__ adjb, const float* __restrict__ cw,
    f16* __restrict__ Oh, float* __restrict__ rsum_ws) {
  __shared__ float lds[4 * WTILE];
  __shared__ float lred[4][64];
  const int gid = blockIdx.x;
  const int bh = gid & 7;
  const int b = bh >> 2, h = bh & 3;
  const int i0 = (gid >> 3) * 64;
  const int tid = threadIdx.x;
  const int lane = tid & 63, jq = tid >> 6;
  const int q = lane >> 4, c = lane & 15;

  // Q fragments + tau for 4 i-groups
  f16x8 a0[4], a1[4];
  float tau_i[4][4];
#pragma unroll
  for (int ig = 0; ig < 4; ++ig) {
    const f16* Qbase = Qh + ((size_t)bh * N_ + i0 + ig * 16 + c) * DH_;
    a0[ig] = *(const f16x8*)(Qbase + q * 8);
    a1[ig] = *(const f16x8*)(Qbase + 32 + q * 8);
#pragma unroll
    for (int r = 0; r < 4; ++r)
      tau_i[ig][r] = tau[b * N_ + i0 + ig * 16 + q * 4 + r];
  }
  const float cw_h = cw[h];  // cb cancels in softmax
  const f16* Kfb = Kf + (size_t)bh * 262144 + lane * 8;
  const f16* Vfb = Vf + (size_t)bh * 262144 + lane * 8;
  const float* taub = tau + b * N_;
  const int jbase = jq * 1024;

  float lsum[4][4] = {};
  f32x4 oacc[4][4] = {};  // [ig][cg]
  float* myp = lds + jq * WTILE;

#pragma unroll 1
  for (int it = 0; it < 16; ++it) {
    const int j0 = jbase + it * 64;
    // ==== tile loads: 8 K frags + 8 V frags, contiguous 1 KB bursts ====
    f16x8 kf[8], vf[8];
    {
      const f16* kt = Kfb + (size_t)(j0 >> 4) * 1024;
#pragma unroll
      for (int f = 0; f < 8; ++f) kf[f] = *(const f16x8*)(kt + f * 512);
    }
    {
      const f16* vt = Vfb + (size_t)(j0 >> 6) * 4096;
#pragma unroll
      for (int f = 0; f < 8; ++f) vf[f] = *(const f16x8*)(vt + f * 512);
    }
    float tj[4];
#pragma unroll
    for (int cg = 0; cg < 4; ++cg) tj[cg] = taub[j0 + cg * 16 + c];

    // ==== 4 i-groups reuse the same kf/vf ====
#pragma unroll
    for (int ig = 0; ig < 4; ++ig) {
      uint2 aw[4];
#pragma unroll
      for (int r = 0; r < 4; ++r)
        aw[r] = adjb[(size_t)(i0 + ig * 16 + q * 4 + r) * 64 + (j0 >> 6)];
      // QK^T -> e = mask*exp(s) -> LDS tile (+ row-sum)
#pragma unroll
      for (int cg = 0; cg < 4; ++cg) {
        f32x4 s = {};
        s = __builtin_amdgcn_mfma_f32_16x16x32_f16(a0[ig], kf[2 * cg], s, 0, 0, 0);
        s = __builtin_amdgcn_mfma_f32_16x16x32_f16(a1[ig], kf[2 * cg + 1], s, 0, 0, 0);
        const float credj = cw_h * tj[cg];
        const unsigned shift = (cg & 1) * 16 + c;
#pragma unroll
        for (int r = 0; r < 4; ++r) {
          unsigned mword = (cg < 2) ? aw[r].x : aw[r].y;
          float e = __expf(s[r] + credj * tau_i[ig][r]);
          e = ((mword >> shift) & 1) ? e : 0.f;
          lsum[ig][r] += e;
          myp[(q * 4 + r) * TS + cg * 16 + c] = e;
        }
      }
      // PV with unnormalized e (A-fragment from own LDS tile)
#pragma unroll
      for (int ks = 0; ks < 2; ++ks) {
        f32x4 plo = *(f32x4*)(myp + c * TS + ks * 32 + q * 8);
        f32x4 phi = *(f32x4*)(myp + c * TS + ks * 32 + q * 8 + 4);
        f16x8 pa;
#pragma unroll
        for (int t = 0; t < 4; ++t) {
          pa[t] = (f16)plo[t];
          pa[4 + t] = (f16)phi[t];
        }
#pragma unroll
        for (int cg = 0; cg < 4; ++cg)
          oacc[ig][cg] = __builtin_amdgcn_mfma_f32_16x16x32_f16(
              pa, vf[ks * 4 + cg], oacc[ig][cg], 0, 0, 0);
      }
    }
  }

  // ---- combine row sums across j-quarters -> linv ----
#pragma unroll
  for (int ig = 0; ig < 4; ++ig) {
#pragma unroll
    for (int r = 0; r < 4; ++r) {
      float v = lsum[ig][r];
      v += __shfl_xor(v, 1);
      v += __shfl_xor(v, 2);
      v += __shfl_xor(v, 4);
      v += __shfl_xor(v, 8);
      lsum[ig][r] = v;
    }
  }
  if (c == 0) {
#pragma unroll
    for (int ig = 0; ig < 4; ++ig)
#pragma unroll
      for (int r = 0; r < 4; ++r) lred[jq][ig * 16 + q * 4 + r] = lsum[ig][r];
  }
  __syncthreads();
  float linv[4][4];
#pragma unroll
  for (int ig = 0; ig < 4; ++ig)
#pragma unroll
    for (int r = 0; r < 4; ++r) {
      int row = ig * 16 + q * 4 + r;
      linv[ig][r] = 1.0f / (lred[0][row] + lred[1][row] + lred[2][row] +
                            lred[3][row]);
    }
  if (jq == 0 && c == 0) {
#pragma unroll
    for (int ig = 0; ig < 4; ++ig)
#pragma unroll
      for (int r = 0; r < 4; ++r)
        rsum_ws[bh * N_ + i0 + ig * 16 + q * 4 + r] = linv[ig][r];
  }

  // ---- combine PV partials across j-quarters (per-ig rounds), write O ----
#pragma unroll 1
  for (int ig = 0; ig < 4; ++ig) {
    if (jq != 0) {
#pragma unroll
      for (int cg = 0; cg < 4; ++cg)
#pragma unroll
        for (int r = 0; r < 4; ++r) myp[(cg * 4 + r) * 64 + lane] = oacc[ig][cg][r];
    }
    __syncthreads();
    if (jq == 0) {
#pragma unroll
      for (int cg = 0; cg < 4; ++cg)
#pragma unroll
        for (int r = 0; r < 4; ++r) {
          float v = oacc[ig][cg][r];
#pragma unroll
          for (int jj = 1; jj < 4; ++jj)
            v += lds[jj * WTILE + (cg * 4 + r) * 64 + lane];
          Oh[((size_t)(b * N_) + i0 + ig * 16 + q * 4 + r) * H_ + h * 64 +
             cg * 16 + c] = (f16)(v * linv[ig][r]);
        }
    }
    __syncthreads();
  }
}

// ---------------- pass B: head-mean via QK^T recompute ----------------
// grid = 1024: gid&1 = b, (gid>>1)&3 = jq (gid&7 XCD-pinned), gid>>3 = i-block
// (32 rows). 4 waves x 4 j-tiles each; per j-tile the 4 heads are unrolled
// (static li/macc indexing) and each head's kf is reused by 2 i-groups.
__global__ __launch_bounds__(256, 2) void attn_mean_kernel(
    const f16* __restrict__ Qh, const f16* __restrict__ Kf,
    const float* __restrict__ tau, const uint2* __restrict__ adjb,
    const float* __restrict__ cw, const float* __restrict__ linv_ws,
    float* __restrict__ out) {
  const int gid = blockIdx.x;
  const int b = gid & 1;
  const int jq = (gid >> 1) & 3;
  const int i0 = (gid >> 3) * 32;
  const int tid = threadIdx.x;
  const int lane = tid & 63, w = tid >> 6;
  const int q = lane >> 4, c = lane & 15;

  // per-row linv*0.25 for all 4 heads x 2 i-groups (held in registers)
  float li[4][2][4];
  float cwh[4];
#pragma unroll
  for (int h = 0; h < 4; ++h) {
    cwh[h] = cw[h];
#pragma unroll
    for (int ig = 0; ig < 2; ++ig)
#pragma unroll
      for (int r = 0; r < 4; ++r)
        li[h][ig][r] =
            linv_ws[(b * 4 + h) * N_ + i0 + ig * 16 + q * 4 + r] * 0.25f;
  }
  float tau_i[2][4];
#pragma unroll
  for (int ig = 0; ig < 2; ++ig)
#pragma unroll
    for (int r = 0; r < 4; ++r)
      tau_i[ig][r] = tau[b * N_ + i0 + ig * 16 + q * 4 + r];
  const float* taub = tau + b * N_;

#pragma unroll 1
  for (int it = 0; it < 4; ++it) {
    const int j0 = jq * 1024 + (it * 4 + w) * 64;
    uint2 aw[2][4];
#pragma unroll
    for (int ig = 0; ig < 2; ++ig)
#pragma unroll
      for (int r = 0; r < 4; ++r)
        aw[ig][r] = adjb[(size_t)(i0 + ig * 16 + q * 4 + r) * 64 + (j0 >> 6)];
    float tj[4];
#pragma unroll
    for (int cg = 0; cg < 4; ++cg) tj[cg] = taub[j0 + cg * 16 + c];

    f32x4 macc[2][4] = {};  // [ig][cg]
#pragma unroll
    for (int h = 0; h < 4; ++h) {
      // K fragments for (head, j-tile): 8 contiguous 1 KB bursts
      f16x8 kf[8];
      {
        const f16* kt = Kf + (size_t)(b * 4 + h) * 262144 +
                        (size_t)(j0 >> 4) * 1024 + lane * 8;
#pragma unroll
        for (int f = 0; f < 8; ++f) kf[f] = *(const f16x8*)(kt + f * 512);
      }
#pragma unroll
      for (int ig = 0; ig < 2; ++ig) {
        // Q fragments reloaded per (h, ig) - L2-hot, 2 x 16 B
        const f16* Qbase =
            Qh + ((size_t)(b * 4 + h) * N_ + i0 + ig * 16 + c) * DH_;
        f16x8 a0 = *(const f16x8*)(Qbase + q * 8);
        f16x8 a1 = *(const f16x8*)(Qbase + 32 + q * 8);
#pragma unroll
        for (int cg = 0; cg < 4; ++cg) {
          f32x4 s = {};
          s = __builtin_amdgcn_mfma_f32_16x16x32_f16(a0, kf[2 * cg], s, 0, 0, 0);
          s = __builtin_amdgcn_mfma_f32_16x16x32_f16(a1, kf[2 * cg + 1], s, 0, 0, 0);
          const float credj = cwh[h] * tj[cg];
          const unsigned shift = (cg & 1) * 16 + c;
#pragma unroll
          for (int r = 0; r < 4; ++r) {
            unsigned mword = (cg < 2) ? aw[ig][r].x : aw[ig][r].y;
            float e = __expf(s[r] + credj * tau_i[ig][r]);
            float lw = ((mword >> shift) & 1) ? li[h][ig][r] : 0.f;
            macc[ig][cg][r] += e * lw;
          }
        }
      }
    }
    // direct store of the 32x64 f32 mean tile (16-lane rows = full 64 B lines)
#pragma unroll
    for (int ig = 0; ig < 2; ++ig)
#pragma unroll
      for (int cg = 0; cg < 4; ++cg)
#pragma unroll
        for (int r = 0; r < 4; ++r)
          out[((size_t)(b * N_) + i0 + ig * 16 + q * 4 + r) * N_ + j0 +
              cg * 16 + c] = macc[ig][cg][r];
  }
}

// Output projection: h_out = O @ Wo^T + bo. grid=(128,4), block=4 waves, 64x64 tile.
__global__ __launch_bounds__(256) void oproj_kernel(
    const f16* __restrict__ Oh, const f16* __restrict__ Woh,
    const float* __restrict__ bo, float* __restrict__ out) {
  const int tid = threadIdx.x, lane = tid & 63, w = tid >> 6;
  const int q = lane >> 4, c = lane & 15;
  const int m0 = blockIdx.x * 64 + w * 16;
  const int o0 = blockIdx.y * 64;
  f32x4 acc[4] = {};
  for (int k0 = 0; k0 < 256; k0 += 32) {
    f16x8 a = *(const f16x8*)(Oh + (size_t)(m0 + c) * 256 + k0 + q * 8);
#pragma unroll
    for (int cg = 0; cg < 4; ++cg) {
      f16x8 bfr = *(const f16x8*)(Woh + (size_t)(o0 + cg * 16 + c) * 256 + k0 + q * 8);
      acc[cg] = __builtin_amdgcn_mfma_f32_16x16x32_f16(a, bfr, acc[cg], 0, 0, 0);
    }
  }
#pragma unroll
  for (int cg = 0; cg < 4; ++cg) {
    float bb = bo[o0 + cg * 16 + c];
#pragma unroll
    for (int r = 0; r < 4; ++r)
      out[(size_t)(m0 + q * 4 + r) * 256 + o0 + cg * 16 + c] = acc[cg][r] + bb;
  }
}

extern "C" void kernel_launch(void* const* d_in, const int* in_sizes, int n_in,
                              void* d_out, int out_size, void* d_ws,
                              size_t ws_size, hipStream_t stream) {
  const float* h   = (const float*)d_in[0];
  const float* tau = (const float*)d_in[1];
  const int*   adj = (const int*)d_in[2];
  const float* Wq  = (const float*)d_in[3];
  const float* bq  = (const float*)d_in[4];
  const float* Wk  = (const float*)d_in[5];
  const float* bk  = (const float*)d_in[6];
  const float* Wv  = (const float*)d_in[7];
  const float* bv  = (const float*)d_in[8];
  const float* cw  = (const float*)d_in[9];
  const float* Wo  = (const float*)d_in[11];
  const float* bo  = (const float*)d_in[12];
  float* out = (float*)d_out;

  f16* ws   = (f16*)d_ws;
  f16* h_h  = ws;
  f16* W_h  = ws + 2097152;
  f16* Wo_h = W_h + 3 * 65536;
  f16* Q_h  = ws + 2359296;
  f16* K_f  = ws + 4456448;
  f16* V_f  = ws + 6553600;
  f16* O_h  = ws + 8650752;
  unsigned long long* adjb = (unsigned long long*)(ws + 10747904);
  float* rsum_ws = (float*)ws;  // reuses dead h_h region (proj runs before attn)

  pack_adj_kernel<<<dim3(65536), dim3(256), 0, stream>>>(adj, adjb);
  cvt_kernel<<<dim3(9216), dim3(256), 0, stream>>>(h, Wq, Wk, Wv, Wo, ws);
  proj_kernel<<<dim3(128, 12), dim3(256), 0, stream>>>(h_h, W_h, bq, bk, bv, Q_h,
                                                       K_f, V_f);
  attn_sum_kernel<<<dim3(512), dim3(256), 0, stream>>>(
      Q_h, K_f, V_f, tau, (const uint2*)adjb, cw, O_h, rsum_ws);
  attn_mean_kernel<<<dim3(1024), dim3(256), 0, stream>>>(
      Q_h, K_f, tau, (const uint2*)adjb, cw, rsum_ws, out + HOUT_OFF);
  oproj_kernel<<<dim3(128, 4), dim3(256), 0, stream>>>(O_h, Wo_h, bo, out);
}

// Round 4
// 391.324 us; speedup vs baseline: 1.6291x; 1.0018x over previous
//
#include <hip/hip_runtime.h>

// Problem constants
#define B_ 2
#define N_ 4096
#define H_ 256
#define HEADS_ 4
#define DH_ 64

typedef _Float16 f16;
typedef f16 f16x8 __attribute__((ext_vector_type(8)));
typedef f16 f16x4 __attribute__((ext_vector_type(4)));
typedef float f32x4 __attribute__((ext_vector_type(4)));

// Workspace layout (units: f16 elements)
//  h_h  : 0         2097152   (dead after proj; rsum_ws f32 reuses this region)
//  W_h  : 2097152   4*65536 (Wq,Wk,Wv,Wo)
//  Q_h  : 2359296   2097152   (b,head,n,dh), pre-scaled by 1/8
//  Kf   : 4456448   2097152   fragment-major K: [bh][t][half] 512-f16 frags
//  Vf   : 6553600   2097152   fragment-major V: [bh][jt][ks*4+cg] 512-f16 frags
//  O_h  : 8650752   2097152   (b,n,256)
//  adjb : 10747904  1048576   2 MB packed adjacency bitmask
// total ~24 MB

#define HOUT_OFF 2097152  // float offset of attn part in d_out

__global__ __launch_bounds__(256) void cvt_kernel(
    const float* __restrict__ h, const float* __restrict__ Wq,
    const float* __restrict__ Wk, const float* __restrict__ Wv,
    const float* __restrict__ Wo, f16* __restrict__ ws) {
  int i = blockIdx.x * 256 + threadIdx.x;
  const int NH = 2097152;
  if (i < NH) {
    ws[i] = (f16)h[i];
  } else if (i < NH + 4 * 65536) {
    int j = i - NH;
    int sel = j >> 16;
    int k = j & 65535;
    const float* src = sel == 0 ? Wq : sel == 1 ? Wk : sel == 2 ? Wv : Wo;
    ws[i] = (f16)src[k];
  }
}

// Pack adj (int32 0/1, NxN) into bit-mask: adjb[row*64 + j/64] bit (j&63).
__global__ __launch_bounds__(256) void pack_adj_kernel(
    const int* __restrict__ adj, unsigned long long* __restrict__ adjb) {
  int g = blockIdx.x * 256 + threadIdx.x;
  int lane = threadIdx.x & 63;
  int av = adj[g] != 0;
  unsigned long long m = __ballot(av);
  if (lane == 0) adjb[g >> 6] = m;
}

// QKV projection. grid=(128, 12): y = wsel*4 + head. Block = 4 waves, tile 64x64.
// K and V are written in FRAGMENT-MAJOR layout so attention waves load them as
// contiguous 1 KB bursts (lane*8) instead of 16-line scattered reads.
__global__ __launch_bounds__(256) void proj_kernel(
    const f16* __restrict__ hh, const f16* __restrict__ Wh,
    const float* __restrict__ bq, const float* __restrict__ bk,
    const float* __restrict__ bv, f16* __restrict__ Qh, f16* __restrict__ Kf,
    f16* __restrict__ Vf) {
  const int tid = threadIdx.x;
  const int lane = tid & 63, w = tid >> 6;
  const int q = lane >> 4, c = lane & 15;
  const int wsel = blockIdx.y >> 2, head = blockIdx.y & 3;
  const int m0 = blockIdx.x * 64 + w * 16;
  const f16* W = Wh + wsel * 65536;
  const int o0 = head * 64;

  f32x4 acc[4] = {};
  for (int k0 = 0; k0 < 256; k0 += 32) {
    f16x8 a = *(const f16x8*)(hh + (size_t)(m0 + c) * 256 + k0 + q * 8);
#pragma unroll
    for (int cg = 0; cg < 4; ++cg) {
      f16x8 bfr = *(const f16x8*)(W + (size_t)(o0 + cg * 16 + c) * 256 + k0 + q * 8);
      acc[cg] = __builtin_amdgcn_mfma_f32_16x16x32_f16(a, bfr, acc[cg], 0, 0, 0);
    }
  }
  const int b = m0 >> 12, n = m0 & 4095;
  const int bh2 = b * HEADS_ + head;
  if (wsel == 2) {
    // V fragment-major: Vf[bh][jt][ks*4+cg][lane_f*8+e],
    // lane_f=(jj>>3&3)*16+c, jj = j mod 64, e = jj&7.
    const int jt = n >> 6;
    f16* vbase = Vf + (((size_t)bh2 * 64 + jt) * 8) * 512;
#pragma unroll
    for (int cg = 0; cg < 4; ++cg) {
      float bb = bv[o0 + cg * 16 + c];
#pragma unroll
      for (int r = 0; r < 4; ++r) {
        int jj = w * 16 + q * 4 + r;
        vbase[(size_t)(((jj >> 5) * 4 + cg) * 512) + ((jj >> 3) & 3) * 128 +
              c * 8 + (jj & 7)] = (f16)(acc[cg][r] + bb);
      }
    }
  } else if (wsel == 1) {
    // K fragment-major: Kf[bh][t][half][lane_f*8+e],
    // lane_f = qf*16 + (row within 16-tile), e = c&7.
    const int t = n >> 4;
    f16* kbase = Kf + (((size_t)bh2 * 256 + t) * 2) * 512;
#pragma unroll
    for (int cg = 0; cg < 4; ++cg) {
      float bb = bk[o0 + cg * 16 + c];
      const int half = cg >> 1;
      const int qf = ((cg & 1) * 16 + c) >> 3;
      f16* kb2 = kbase + half * 512 + qf * 128 + (c & 7);
#pragma unroll
      for (int r = 0; r < 4; ++r) kb2[(q * 4 + r) * 8] = (f16)(acc[cg][r] + bb);
    }
  } else {
    // Q keeps (n, dh) layout, pre-scaled by 1/8
#pragma unroll
    for (int cg = 0; cg < 4; ++cg) {
      int dh = cg * 16 + c;
      float bb = bq[o0 + dh];
#pragma unroll
      for (int r = 0; r < 4; ++r)
        Qh[((size_t)bh2 * N_ + n + q * 4 + r) * DH_ + dh] =
            (f16)((acc[cg][r] + bb) * 0.125f);
    }
  }
}

#define TS 68  // LDS p-tile row stride (f32); rows 16B-aligned (68*4=272=17*16)
#define WTILE (16 * TS)

// ---------------- pass A: row-sums (linv) + PV -> O ----------------
// grid = 512 blocks: bh = gid&7 (XCD-pinned: K+V of one bh = 1 MB, L2-hot),
// i-block = gid>>3 (64 rows). Block = 4 waves = 4 j-quarters; each wave
// processes 4 i-groups (64 Q rows) per K/V tile -> 4x load amortization and
// 4 independent MFMA/exp chains for latency hiding.
// __launch_bounds__(256,1): allow up to 256 VGPR — (256,2) capped at 128 and
// spilled ~100 MB of scratch traffic per dispatch (R3 counters).
__global__ __launch_bounds__(256, 1) void attn_sum_kernel(
    const f16* __restrict__ Qh, const f16* __restrict__ Kf,
    const f16* __restrict__ Vf, const float* __restrict__ tau,
    const uint2* __restrict__ adjb, const float* __restrict__ cw,
    f16* __restrict__ Oh, float* __restrict__ rsum_ws) {
  __shared__ float lds[4 * WTILE];
  __shared__ float lred[4][64];
  const int gid = blockIdx.x;
  const int bh = gid & 7;
  const int b = bh >> 2, h = bh & 3;
  const int i0 = (gid >> 3) * 64;
  const int tid = threadIdx.x;
  const int lane = tid & 63, jq = tid >> 6;
  const int q = lane >> 4, c = lane & 15;

  // Q fragments + tau for 4 i-groups
  f16x8 a0[4], a1[4];
  float tau_i[4][4];
#pragma unroll
  for (int ig = 0; ig < 4; ++ig) {
    const f16* Qbase = Qh + ((size_t)bh * N_ + i0 + ig * 16 + c) * DH_;
    a0[ig] = *(const f16x8*)(Qbase + q * 8);
    a1[ig] = *(const f16x8*)(Qbase + 32 + q * 8);
#pragma unroll
    for (int r = 0; r < 4; ++r)
      tau_i[ig][r] = tau[b * N_ + i0 + ig * 16 + q * 4 + r];
  }
  const float cw_h = cw[h];  // cb cancels in softmax
  const f16* Kfb = Kf + (size_t)bh * 262144 + lane * 8;
  const f16* Vfb = Vf + (size_t)bh * 262144 + lane * 8;
  const float* taub = tau + b * N_;
  const int jbase = jq * 1024;

  float lsum[4][4] = {};
  f32x4 oacc[4][4] = {};  // [ig][cg]
  float* myp = lds + jq * WTILE;

#pragma unroll 1
  for (int it = 0; it < 16; ++it) {
    const int j0 = jbase + it * 64;
    // ==== tile loads: 8 K frags + 8 V frags, contiguous 1 KB bursts ====
    f16x8 kf[8], vf[8];
    {
      const f16* kt = Kfb + (size_t)(j0 >> 4) * 1024;
#pragma unroll
      for (int f = 0; f < 8; ++f) kf[f] = *(const f16x8*)(kt + f * 512);
    }
    {
      const f16* vt = Vfb + (size_t)(j0 >> 6) * 4096;
#pragma unroll
      for (int f = 0; f < 8; ++f) vf[f] = *(const f16x8*)(vt + f * 512);
    }
    float tj[4];
#pragma unroll
    for (int cg = 0; cg < 4; ++cg) tj[cg] = taub[j0 + cg * 16 + c];

    // ==== 4 i-groups reuse the same kf/vf ====
#pragma unroll
    for (int ig = 0; ig < 4; ++ig) {
      uint2 aw[4];
#pragma unroll
      for (int r = 0; r < 4; ++r)
        aw[r] = adjb[(size_t)(i0 + ig * 16 + q * 4 + r) * 64 + (j0 >> 6)];
      // QK^T -> e = mask*exp(s) -> LDS tile (+ row-sum)
#pragma unroll
      for (int cg = 0; cg < 4; ++cg) {
        f32x4 s = {};
        s = __builtin_amdgcn_mfma_f32_16x16x32_f16(a0[ig], kf[2 * cg], s, 0, 0, 0);
        s = __builtin_amdgcn_mfma_f32_16x16x32_f16(a1[ig], kf[2 * cg + 1], s, 0, 0, 0);
        const float credj = cw_h * tj[cg];
        const unsigned shift = (cg & 1) * 16 + c;
#pragma unroll
        for (int r = 0; r < 4; ++r) {
          unsigned mword = (cg < 2) ? aw[r].x : aw[r].y;
          float e = __expf(s[r] + credj * tau_i[ig][r]);
          e = ((mword >> shift) & 1) ? e : 0.f;
          lsum[ig][r] += e;
          myp[(q * 4 + r) * TS + cg * 16 + c] = e;
        }
      }
      // PV with unnormalized e (A-fragment from own LDS tile)
#pragma unroll
      for (int ks = 0; ks < 2; ++ks) {
        f32x4 plo = *(f32x4*)(myp + c * TS + ks * 32 + q * 8);
        f32x4 phi = *(f32x4*)(myp + c * TS + ks * 32 + q * 8 + 4);
        f16x8 pa;
#pragma unroll
        for (int t = 0; t < 4; ++t) {
          pa[t] = (f16)plo[t];
          pa[4 + t] = (f16)phi[t];
        }
#pragma unroll
        for (int cg = 0; cg < 4; ++cg)
          oacc[ig][cg] = __builtin_amdgcn_mfma_f32_16x16x32_f16(
              pa, vf[ks * 4 + cg], oacc[ig][cg], 0, 0, 0);
      }
    }
  }

  // ---- combine row sums across j-quarters -> linv ----
#pragma unroll
  for (int ig = 0; ig < 4; ++ig) {
#pragma unroll
    for (int r = 0; r < 4; ++r) {
      float v = lsum[ig][r];
      v += __shfl_xor(v, 1);
      v += __shfl_xor(v, 2);
      v += __shfl_xor(v, 4);
      v += __shfl_xor(v, 8);
      lsum[ig][r] = v;
    }
  }
  if (c == 0) {
#pragma unroll
    for (int ig = 0; ig < 4; ++ig)
#pragma unroll
      for (int r = 0; r < 4; ++r) lred[jq][ig * 16 + q * 4 + r] = lsum[ig][r];
  }
  __syncthreads();
  float linv[4][4];
#pragma unroll
  for (int ig = 0; ig < 4; ++ig)
#pragma unroll
    for (int r = 0; r < 4; ++r) {
      int row = ig * 16 + q * 4 + r;
      linv[ig][r] = 1.0f / (lred[0][row] + lred[1][row] + lred[2][row] +
                            lred[3][row]);
    }
  if (jq == 0 && c == 0) {
#pragma unroll
    for (int ig = 0; ig < 4; ++ig)
#pragma unroll
      for (int r = 0; r < 4; ++r)
        rsum_ws[bh * N_ + i0 + ig * 16 + q * 4 + r] = linv[ig][r];
  }

  // ---- combine PV partials across j-quarters (per-ig rounds), write O ----
#pragma unroll 1
  for (int ig = 0; ig < 4; ++ig) {
    if (jq != 0) {
#pragma unroll
      for (int cg = 0; cg < 4; ++cg)
#pragma unroll
        for (int r = 0; r < 4; ++r) myp[(cg * 4 + r) * 64 + lane] = oacc[ig][cg][r];
    }
    __syncthreads();
    if (jq == 0) {
#pragma unroll
      for (int cg = 0; cg < 4; ++cg)
#pragma unroll
        for (int r = 0; r < 4; ++r) {
          float v = oacc[ig][cg][r];
#pragma unroll
          for (int jj = 1; jj < 4; ++jj)
            v += lds[jj * WTILE + (cg * 4 + r) * 64 + lane];
          Oh[((size_t)(b * N_) + i0 + ig * 16 + q * 4 + r) * H_ + h * 64 +
             cg * 16 + c] = (f16)(v * linv[ig][r]);
        }
    }
    __syncthreads();
  }
}

// ---------------- pass B: head-mean via QK^T recompute ----------------
// grid = 1024: gid&1 = b, (gid>>1)&3 = jq (gid&7 XCD-pinned), gid>>3 = i-block
// (32 rows). 4 waves x 4 j-tiles each; per j-tile the 4 heads are unrolled
// (static li/macc indexing) and each head's kf is reused by 2 i-groups.
// (256,1): same spill fix as attn_sum.
__global__ __launch_bounds__(256, 1) void attn_mean_kernel(
    const f16* __restrict__ Qh, const f16* __restrict__ Kf,
    const float* __restrict__ tau, const uint2* __restrict__ adjb,
    const float* __restrict__ cw, const float* __restrict__ linv_ws,
    float* __restrict__ out) {
  const int gid = blockIdx.x;
  const int b = gid & 1;
  const int jq = (gid >> 1) & 3;
  const int i0 = (gid >> 3) * 32;
  const int tid = threadIdx.x;
  const int lane = tid & 63, w = tid >> 6;
  const int q = lane >> 4, c = lane & 15;

  // per-row linv*0.25 for all 4 heads x 2 i-groups (held in registers)
  float li[4][2][4];
  float cwh[4];
#pragma unroll
  for (int h = 0; h < 4; ++h) {
    cwh[h] = cw[h];
#pragma unroll
    for (int ig = 0; ig < 2; ++ig)
#pragma unroll
      for (int r = 0; r < 4; ++r)
        li[h][ig][r] =
            linv_ws[(b * 4 + h) * N_ + i0 + ig * 16 + q * 4 + r] * 0.25f;
  }
  float tau_i[2][4];
#pragma unroll
  for (int ig = 0; ig < 2; ++ig)
#pragma unroll
    for (int r = 0; r < 4; ++r)
      tau_i[ig][r] = tau[b * N_ + i0 + ig * 16 + q * 4 + r];
  const float* taub = tau + b * N_;

#pragma unroll 1
  for (int it = 0; it < 4; ++it) {
    const int j0 = jq * 1024 + (it * 4 + w) * 64;
    uint2 aw[2][4];
#pragma unroll
    for (int ig = 0; ig < 2; ++ig)
#pragma unroll
      for (int r = 0; r < 4; ++r)
        aw[ig][r] = adjb[(size_t)(i0 + ig * 16 + q * 4 + r) * 64 + (j0 >> 6)];
    float tj[4];
#pragma unroll
    for (int cg = 0; cg < 4; ++cg) tj[cg] = taub[j0 + cg * 16 + c];

    f32x4 macc[2][4] = {};  // [ig][cg]
#pragma unroll
    for (int h = 0; h < 4; ++h) {
      // K fragments for (head, j-tile): 8 contiguous 1 KB bursts
      f16x8 kf[8];
      {
        const f16* kt = Kf + (size_t)(b * 4 + h) * 262144 +
                        (size_t)(j0 >> 4) * 1024 + lane * 8;
#pragma unroll
        for (int f = 0; f < 8; ++f) kf[f] = *(const f16x8*)(kt + f * 512);
      }
#pragma unroll
      for (int ig = 0; ig < 2; ++ig) {
        // Q fragments reloaded per (h, ig) - L2-hot, 2 x 16 B
        const f16* Qbase =
            Qh + ((size_t)(b * 4 + h) * N_ + i0 + ig * 16 + c) * DH_;
        f16x8 a0 = *(const f16x8*)(Qbase + q * 8);
        f16x8 a1 = *(const f16x8*)(Qbase + 32 + q * 8);
#pragma unroll
        for (int cg = 0; cg < 4; ++cg) {
          f32x4 s = {};
          s = __builtin_amdgcn_mfma_f32_16x16x32_f16(a0, kf[2 * cg], s, 0, 0, 0);
          s = __builtin_amdgcn_mfma_f32_16x16x32_f16(a1, kf[2 * cg + 1], s, 0, 0, 0);
          const float credj = cwh[h] * tj[cg];
          const unsigned shift = (cg & 1) * 16 + c;
#pragma unroll
          for (int r = 0; r < 4; ++r) {
            unsigned mword = (cg < 2) ? aw[ig][r].x : aw[ig][r].y;
            float e = __expf(s[r] + credj * tau_i[ig][r]);
            float lw = ((mword >> shift) & 1) ? li[h][ig][r] : 0.f;
            macc[ig][cg][r] += e * lw;
          }
        }
      }
    }
    // direct store of the 32x64 f32 mean tile (16-lane rows = full 64 B lines)
#pragma unroll
    for (int ig = 0; ig < 2; ++ig)
#pragma unroll
      for (int cg = 0; cg < 4; ++cg)
#pragma unroll
        for (int r = 0; r < 4; ++r)
          out[((size_t)(b * N_) + i0 + ig * 16 + q * 4 + r) * N_ + j0 +
              cg * 16 + c] = macc[ig][cg][r];
  }
}

// Output projection: h_out = O @ Wo^T + bo. grid=(128,4), block=4 waves, 64x64 tile.
__global__ __launch_bounds__(256) void oproj_kernel(
    const f16* __restrict__ Oh, const f16* __restrict__ Woh,
    const float* __restrict__ bo, float* __restrict__ out) {
  const int tid = threadIdx.x, lane = tid & 63, w = tid >> 6;
  const int q = lane >> 4, c = lane & 15;
  const int m0 = blockIdx.x * 64 + w * 16;
  const int o0 = blockIdx.y * 64;
  f32x4 acc[4] = {};
  for (int k0 = 0; k0 < 256; k0 += 32) {
    f16x8 a = *(const f16x8*)(Oh + (size_t)(m0 + c) * 256 + k0 + q * 8);
#pragma unroll
    for (int cg = 0; cg < 4; ++cg) {
      f16x8 bfr = *(const f16x8*)(Woh + (size_t)(o0 + cg * 16 + c) * 256 + k0 + q * 8);
      acc[cg] = __builtin_amdgcn_mfma_f32_16x16x32_f16(a, bfr, acc[cg], 0, 0, 0);
    }
  }
#pragma unroll
  for (int cg = 0; cg < 4; ++cg) {
    float bb = bo[o0 + cg * 16 + c];
#pragma unroll
    for (int r = 0; r < 4; ++r)
      out[(size_t)(m0 + q * 4 + r) * 256 + o0 + cg * 16 + c] = acc[cg][r] + bb;
  }
}

extern "C" void kernel_launch(void* const* d_in, const int* in_sizes, int n_in,
                              void* d_out, int out_size, void* d_ws,
                              size_t ws_size, hipStream_t stream) {
  const float* h   = (const float*)d_in[0];
  const float* tau = (const float*)d_in[1];
  const int*   adj = (const int*)d_in[2];
  const float* Wq  = (const float*)d_in[3];
  const float* bq  = (const float*)d_in[4];
  const float* Wk  = (const float*)d_in[5];
  const float* bk  = (const float*)d_in[6];
  const float* Wv  = (const float*)d_in[7];
  const float* bv  = (const float*)d_in[8];
  const float* cw  = (const float*)d_in[9];
  const float* Wo  = (const float*)d_in[11];
  const float* bo  = (const float*)d_in[12];
  float* out = (float*)d_out;

  f16* ws   = (f16*)d_ws;
  f16* h_h  = ws;
  f16* W_h  = ws + 2097152;
  f16* Wo_h = W_h + 3 * 65536;
  f16* Q_h  = ws + 2359296;
  f16* K_f  = ws + 4456448;
  f16* V_f  = ws + 6553600;
  f16* O_h  = ws + 8650752;
  unsigned long long* adjb = (unsigned long long*)(ws + 10747904);
  float* rsum_ws = (float*)ws;  // reuses dead h_h region (proj runs before attn)

  pack_adj_kernel<<<dim3(65536), dim3(256), 0, stream>>>(adj, adjb);
  cvt_kernel<<<dim3(9216), dim3(256), 0, stream>>>(h, Wq, Wk, Wv, Wo, ws);
  proj_kernel<<<dim3(128, 12), dim3(256), 0, stream>>>(h_h, W_h, bq, bk, bv, Q_h,
                                                       K_f, V_f);
  attn_sum_kernel<<<dim3(512), dim3(256), 0, stream>>>(
      Q_h, K_f, V_f, tau, (const uint2*)adjb, cw, O_h, rsum_ws);
  attn_mean_kernel<<<dim3(1024), dim3(256), 0, stream>>>(
      Q_h, K_f, tau, (const uint2*)adjb, cw, rsum_ws, out + HOUT_OFF);
  oproj_kernel<<<dim3(128, 4), dim3(256), 0, stream>>>(O_h, Wo_h, bo, out);
}